// Round 1
// baseline (13735.651 us; speedup 1.0000x reference)
//
#include <hip/hip_runtime.h>
#include <stdint.h>
#include <stddef.h>

#define TSEQ 512
#define NB   64
#define DI   1024
#define DHID 1024
#define NG   4096
#define NWG  128   // recurrent workgroups (8 hidden units each)

typedef __attribute__((ext_vector_type(8))) short short8;
typedef __attribute__((ext_vector_type(4))) float f32x4;

__device__ __forceinline__ unsigned short f2bf(float f) {
  union { float f; uint32_t u; } v; v.f = f;
  uint32_t u = v.u;
  uint32_t r = u + 0x7fffu + ((u >> 16) & 1u);
  return (unsigned short)(r >> 16);
}
__device__ __forceinline__ float bf2f(unsigned short b) {
  union { uint32_t u; float f; } v; v.u = ((uint32_t)b) << 16;
  return v.f;
}
__device__ __forceinline__ float fsigm(float x) { return 1.0f / (1.0f + __expf(-x)); }
__device__ __forceinline__ float ftanh(float x) { return 1.0f - 2.0f / (__expf(2.0f * x) + 1.0f); }

__device__ __forceinline__ void gll16(const void* g, void* l) {
  __builtin_amdgcn_global_load_lds(
      (const __attribute__((address_space(1))) void*)g,
      (__attribute__((address_space(3))) void*)l, 16, 0, 0);
}

// ---------------- K1: x fp32 -> bf16 ----------------
__global__ void k_convert_x(const float* __restrict__ x, unsigned short* __restrict__ xb, int n4) {
  int idx = blockIdx.x * blockDim.x + threadIdx.x;
  int stride = gridDim.x * blockDim.x;
  const float4* xf = (const float4*)x;
  for (int i = idx; i < n4; i += stride) {
    float4 v = xf[i];
    unsigned short o0 = f2bf(v.x), o1 = f2bf(v.y), o2 = f2bf(v.z), o3 = f2bf(v.w);
    uint2 packed;
    packed.x = (uint32_t)o0 | ((uint32_t)o1 << 16);
    packed.y = (uint32_t)o2 | ((uint32_t)o3 << 16);
    ((uint2*)xb)[i] = packed;
  }
}

// ---------------- K2: transpose W [1024][4096] fp32 -> [4096][1024] bf16 ----------------
__global__ void k_transpose_w(const float* __restrict__ w, unsigned short* __restrict__ wt) {
  __shared__ float tile[32][33];
  int n0 = blockIdx.x * 32;
  int k0 = blockIdx.y * 32;
  int c = threadIdx.x & 31, r0 = threadIdx.x >> 5;
  for (int r = r0; r < 32; r += 8)
    tile[r][c] = w[(size_t)(k0 + r) * NG + n0 + c];
  __syncthreads();
  for (int r = r0; r < 32; r += 8)
    wt[(size_t)(n0 + r) * 1024 + k0 + c] = f2bf(tile[c][r]);
}

// ---------------- K3: init (h0->bf16 buf0, bsum, counter) ----------------
__global__ void k_init(const float* __restrict__ h0, const float* __restrict__ b_ih,
                       const float* __restrict__ b_hh, unsigned short* __restrict__ hbuf0,
                       float* __restrict__ bsum, unsigned* __restrict__ ctr) {
  int i = blockIdx.x * 256 + threadIdx.x;
  if (i < NB * DHID) hbuf0[i] = f2bf(h0[i]);
  if (i < NG) bsum[i] = b_ih[i] + b_hh[i];
  if (i == 0) *ctr = 0u;
}

// ---------------- K4: pregate GEMM  pg = x_bf16 @ W_ih (permuted layout) ----------------
// A = xb [32768][1024] bf16, B^T = wihT [4096][1024] bf16.
// Output permuted: idx = ((t*128 + wg)*2048) + b*32 + g*8 + u  (wg=j>>3, u=j&7, j=col%1024, g=col/1024)
template <bool PF32>
__global__ __launch_bounds__(256, 2) void k_gemm_pregates(
    const unsigned short* __restrict__ xb,
    const unsigned short* __restrict__ wt,
    void* __restrict__ pg) {
  __shared__ char lds_raw[32768];  // A: 16KB swizzled, B: 16KB swizzled
  char* As = lds_raw;
  char* Bs = lds_raw + 16384;

  const int wave = threadIdx.x >> 6;
  const int lane = threadIdx.x & 63;
  const int ln = lane & 15, quad = lane >> 4;
  const int m0 = blockIdx.x * 128;
  const int n0 = blockIdx.y * 128;
  const int mw = (wave >> 1) * 64, nw = (wave & 1) * 64;

  f32x4 acc[4][4] = {};

  for (int kc = 0; kc < 16; ++kc) {
    __syncthreads();
    // stage 128x64(bf16) A tile and B^T tile, 16B-swizzled:
    // slot s (0..1023): row=s>>3, kg = (s&7) ^ (row&7); lds off = s*16
#pragma unroll
    for (int i = 0; i < 4; ++i) {
      int s = wave * 256 + i * 64 + lane;
      int row = s >> 3;
      int kg = (s & 7) ^ (row & 7);
      gll16(xb + (size_t)(m0 + row) * 1024 + kc * 64 + kg * 8, As + s * 16);
      gll16(wt + (size_t)(n0 + row) * 1024 + kc * 64 + kg * 8, Bs + s * 16);
    }
    __syncthreads();

    short8 a[2][4], b[2][4];
#pragma unroll
    for (int kt = 0; kt < 2; ++kt) {
      int kg = kt * 4 + quad;
#pragma unroll
      for (int mt = 0; mt < 4; ++mt) {
        int row = mw + mt * 16 + ln;
        a[kt][mt] = *(const short8*)(As + (row * 8 + (kg ^ (row & 7))) * 16);
      }
#pragma unroll
      for (int nt = 0; nt < 4; ++nt) {
        int row = nw + nt * 16 + ln;
        b[kt][nt] = *(const short8*)(Bs + (row * 8 + (kg ^ (row & 7))) * 16);
      }
    }
#pragma unroll
    for (int kt = 0; kt < 2; ++kt)
#pragma unroll
      for (int mt = 0; mt < 4; ++mt)
#pragma unroll
        for (int nt = 0; nt < 4; ++nt)
          acc[mt][nt] = __builtin_amdgcn_mfma_f32_16x16x32_bf16(a[kt][mt], b[kt][nt], acc[mt][nt], 0, 0, 0);
  }

  // epilogue: permuted store
#pragma unroll
  for (int mt = 0; mt < 4; ++mt)
#pragma unroll
    for (int nt = 0; nt < 4; ++nt)
#pragma unroll
      for (int r = 0; r < 4; ++r) {
        int rowg = m0 + mw + mt * 16 + quad * 4 + r;
        int colg = n0 + nw + nt * 16 + ln;
        int t = rowg >> 6, bb = rowg & 63;
        int g = colg >> 10, j = colg & 1023;
        int wg = j >> 3, u = j & 7;
        size_t idx = ((size_t)t * NWG + wg) * 2048 + bb * 32 + g * 8 + u;
        if (PF32)
          ((float*)pg)[idx] = acc[mt][nt][r];
        else
          ((unsigned short*)pg)[idx] = f2bf(acc[mt][nt][r]);
      }
}

__device__ __forceinline__ float ldpg_f(const float* p, size_t i) { return p[i]; }
__device__ __forceinline__ float ldpg_b(const unsigned short* p, size_t i) { return bf2f(p[i]); }

// ---------------- K5: persistent recurrent kernel ----------------
// 128 WGs x 256 threads. WG wg owns hidden units [wg*8, wg*8+8) -> 32 gate cols.
// Wave = mtile (16 batch rows); each wave computes both 16-col N-tiles; W_hh slice in VGPRs.
template <bool PF32>
__global__ __launch_bounds__(256, 1) void k_lstm(
    const unsigned short* __restrict__ whhT,  // [4096][1024] bf16
    const void* __restrict__ pg,
    const float* __restrict__ c0,
    const float* __restrict__ bsum,
    unsigned short* __restrict__ hbuf,  // [2][64][1024] bf16
    float* __restrict__ out,            // [512][64][1024] ++ h_last ++ c_last
    unsigned* __restrict__ ctr) {
  const int wg = blockIdx.x;
  const int tid = threadIdx.x;
  const int wave = tid >> 6, lane = tid & 63;
  const int ln = lane & 15, quad = lane >> 4;

  __shared__ float gl[64 * 36];  // gates [64 batch][32 cols], stride 36 (bank spread)

  // --- load W_hh fragments into registers (persistent across all timesteps) ---
  short8 wfr[2][32];
#pragma unroll
  for (int nt = 0; nt < 2; ++nt) {
    int col32 = nt * 16 + ln;
    int g = col32 >> 3, u = col32 & 7;
    const unsigned short* wrow = whhT + (size_t)(g * 1024 + wg * 8 + u) * 1024;
#pragma unroll
    for (int kt = 0; kt < 32; ++kt)
      wfr[nt][kt] = *(const short8*)(wrow + kt * 32 + quad * 8);
  }

  // --- c state + biases in registers (2 elements per thread) ---
  float cst[2], bs[2][4];
#pragma unroll
  for (int e = 0; e < 2; ++e) {
    int idx = tid + e * 256;
    int b = idx >> 3, u = idx & 7;
    cst[e] = c0[(size_t)b * DHID + wg * 8 + u];
#pragma unroll
    for (int g = 0; g < 4; ++g) bs[e][g] = bsum[g * 1024 + wg * 8 + u];
  }

  const size_t out_hlast = (size_t)TSEQ * NB * DHID;
  const size_t out_clast = out_hlast + (size_t)NB * DHID;

  for (int t = 0; t < TSEQ; ++t) {
    const unsigned short* hin = hbuf + (size_t)(t & 1) * (NB * DHID);
    unsigned short* hout = hbuf + (size_t)((t + 1) & 1) * (NB * DHID);

    // ---- gates_slice = h @ Whh_slice  (A read directly from global h buffer) ----
    f32x4 acc0 = {0.f, 0.f, 0.f, 0.f}, acc1 = {0.f, 0.f, 0.f, 0.f};
    const unsigned short* arow = hin + (size_t)(wave * 16 + ln) * 1024 + quad * 8;
#pragma unroll
    for (int kt = 0; kt < 32; ++kt) {
      short8 a = *(const short8*)(arow + kt * 32);
      acc0 = __builtin_amdgcn_mfma_f32_16x16x32_bf16(a, wfr[0][kt], acc0, 0, 0, 0);
      acc1 = __builtin_amdgcn_mfma_f32_16x16x32_bf16(a, wfr[1][kt], acc1, 0, 0, 0);
    }

    // ---- accumulators -> LDS ----
    {
      int grow = wave * 16 + quad * 4;
#pragma unroll
      for (int r = 0; r < 4; ++r) {
        gl[(grow + r) * 36 + ln] = acc0[r];
        gl[(grow + r) * 36 + 16 + ln] = acc1[r];
      }
    }
    __syncthreads();

    // ---- fused gate activation + state update ----
#pragma unroll
    for (int e = 0; e < 2; ++e) {
      int idx = tid + e * 256;
      int b = idx >> 3, u = idx & 7;
      size_t pgbase = ((size_t)t * NWG + wg) * 2048 + (size_t)b * 32 + u;
      float p0, p1, p2, p3;
      if (PF32) {
        const float* pp = (const float*)pg;
        p0 = ldpg_f(pp, pgbase); p1 = ldpg_f(pp, pgbase + 8);
        p2 = ldpg_f(pp, pgbase + 16); p3 = ldpg_f(pp, pgbase + 24);
      } else {
        const unsigned short* pp = (const unsigned short*)pg;
        p0 = ldpg_b(pp, pgbase); p1 = ldpg_b(pp, pgbase + 8);
        p2 = ldpg_b(pp, pgbase + 16); p3 = ldpg_b(pp, pgbase + 24);
      }
      float gi = gl[b * 36 + u] + p0 + bs[e][0];
      float gf = gl[b * 36 + 8 + u] + p1 + bs[e][1];
      float gg = gl[b * 36 + 16 + u] + p2 + bs[e][2];
      float go = gl[b * 36 + 24 + u] + p3 + bs[e][3];
      float i_ = fsigm(gi), f_ = fsigm(gf), g_ = ftanh(gg), o_ = fsigm(go);
      float cn = f_ * cst[e] + i_ * g_;
      cst[e] = cn;
      float h = o_ * ftanh(cn);
      size_t oidx = ((size_t)t * NB + b) * DHID + wg * 8 + u;
      out[oidx] = h;
      hout[(size_t)b * DHID + wg * 8 + u] = f2bf(h);
      if (t == TSEQ - 1) {
        out[out_hlast + (size_t)b * DHID + wg * 8 + u] = h;
        out[out_clast + (size_t)b * DHID + wg * 8 + u] = cn;
      }
    }

    // ---- device-scope barrier (cross-XCD safe) ----
    __threadfence();
    __syncthreads();
    if (tid == 0) {
      __hip_atomic_fetch_add(ctr, 1u, __ATOMIC_RELEASE, __HIP_MEMORY_SCOPE_AGENT);
      unsigned tgt = (unsigned)NWG * (unsigned)(t + 1);
      while (__hip_atomic_load(ctr, __ATOMIC_ACQUIRE, __HIP_MEMORY_SCOPE_AGENT) < tgt)
        __builtin_amdgcn_s_sleep(1);
    }
    __syncthreads();
  }
}

// ---------------- launcher ----------------
static inline size_t align_up(size_t x, size_t a) { return (x + a - 1) & ~(a - 1); }

extern "C" void kernel_launch(void* const* d_in, const int* in_sizes, int n_in,
                              void* d_out, int out_size, void* d_ws, size_t ws_size,
                              hipStream_t stream) {
  const float* x    = (const float*)d_in[0];
  const float* c0   = (const float*)d_in[1];
  const float* h0   = (const float*)d_in[2];
  const float* W_ih = (const float*)d_in[3];
  const float* W_hh = (const float*)d_in[4];
  const float* b_ih = (const float*)d_in[5];
  const float* b_hh = (const float*)d_in[6];
  float* out = (float*)d_out;

  const size_t pg_elems = (size_t)TSEQ * NB * NG;       // 134,217,728
  const size_t xb_bytes = (size_t)TSEQ * NB * DI * 2;   // 64 MB
  const size_t wt_bytes = (size_t)NG * 1024 * 2;        // 8 MB each
  const size_t hb_bytes = (size_t)2 * NB * DHID * 2;    // 256 KB
  const size_t bsum_bytes = (size_t)NG * 4;             // 16 KB

  auto layout = [&](size_t pg_bytes, size_t* offs) {
    size_t o = 0;
    offs[0] = o; o = align_up(o + pg_bytes, 256);   // pregates
    offs[1] = o; o = align_up(o + xb_bytes, 256);   // x bf16
    offs[2] = o; o = align_up(o + wt_bytes, 256);   // WihT
    offs[3] = o; o = align_up(o + wt_bytes, 256);   // WhhT
    offs[4] = o; o = align_up(o + hb_bytes, 256);   // hbuf
    offs[5] = o; o = align_up(o + bsum_bytes, 256); // bsum
    offs[6] = o; o = align_up(o + 64, 256);         // counter
    return o;
  };
  size_t offs[7];
  size_t need_f32 = layout(pg_elems * 4, offs);
  bool pf32 = ws_size >= need_f32;
  if (!pf32) layout(pg_elems * 2, offs);

  char* ws = (char*)d_ws;
  void* pg = ws + offs[0];
  unsigned short* xb   = (unsigned short*)(ws + offs[1]);
  unsigned short* wihT = (unsigned short*)(ws + offs[2]);
  unsigned short* whhT = (unsigned short*)(ws + offs[3]);
  unsigned short* hbuf = (unsigned short*)(ws + offs[4]);
  float* bsum = (float*)(ws + offs[5]);
  unsigned* ctr = (unsigned*)(ws + offs[6]);

  // prep
  k_convert_x<<<2048, 256, 0, stream>>>(x, xb, (int)((size_t)TSEQ * NB * DI / 4));
  k_transpose_w<<<dim3(NG / 32, 1024 / 32), 256, 0, stream>>>(W_ih, wihT);
  k_transpose_w<<<dim3(NG / 32, 1024 / 32), 256, 0, stream>>>(W_hh, whhT);
  k_init<<<(NB * DHID + 255) / 256, 256, 0, stream>>>(h0, b_ih, b_hh, hbuf, bsum, ctr);

  // pregate GEMM
  dim3 ggrid(TSEQ * NB / 128, NG / 128);
  if (pf32)
    k_gemm_pregates<true><<<ggrid, 256, 0, stream>>>(xb, wihT, pg);
  else
    k_gemm_pregates<false><<<ggrid, 256, 0, stream>>>(xb, wihT, pg);

  // persistent recurrence
  if (pf32)
    k_lstm<true><<<NWG, 256, 0, stream>>>(whhT, pg, c0, bsum, hbuf, out, ctr);
  else
    k_lstm<false><<<NWG, 256, 0, stream>>>(whhT, pg, c0, bsum, hbuf, out, ctr);
}

// Round 3
// 7357.079 us; speedup vs baseline: 1.8670x; 1.8670x over previous
//
#include <hip/hip_runtime.h>
#include <stdint.h>
#include <stddef.h>

#define TSEQ 512
#define NB   64
#define DI   1024
#define DHID 1024
#define NG   4096
#define NGRP 4     // independent batch groups (16 batch rows each)
#define WPG  64    // workgroups per group (16 hidden units each)
#define NWGS 256   // total persistent workgroups (1 per CU)

typedef __attribute__((ext_vector_type(8))) short short8;
typedef __attribute__((ext_vector_type(4))) float f32x4;

__device__ __forceinline__ unsigned short f2bf(float f) {
  union { float f; uint32_t u; } v; v.f = f;
  uint32_t u = v.u;
  uint32_t r = u + 0x7fffu + ((u >> 16) & 1u);
  return (unsigned short)(r >> 16);
}
__device__ __forceinline__ float bf2f(unsigned short b) {
  union { uint32_t u; float f; } v; v.u = ((uint32_t)b) << 16;
  return v.f;
}
__device__ __forceinline__ float fsigm(float x) { return 1.0f / (1.0f + __expf(-x)); }
__device__ __forceinline__ float ftanh(float x) { return 1.0f - 2.0f / (__expf(2.0f * x) + 1.0f); }

__device__ __forceinline__ void gll16(const void* g, void* l) {
  __builtin_amdgcn_global_load_lds(
      (const __attribute__((address_space(1))) void*)g,
      (__attribute__((address_space(3))) void*)l, 16, 0, 0);
}

// ---------------- K1: x fp32 -> bf16 ----------------
__global__ void k_convert_x(const float* __restrict__ x, unsigned short* __restrict__ xb, int n4) {
  int idx = blockIdx.x * blockDim.x + threadIdx.x;
  int stride = gridDim.x * blockDim.x;
  const float4* xf = (const float4*)x;
  for (int i = idx; i < n4; i += stride) {
    float4 v = xf[i];
    unsigned short o0 = f2bf(v.x), o1 = f2bf(v.y), o2 = f2bf(v.z), o3 = f2bf(v.w);
    uint2 packed;
    packed.x = (uint32_t)o0 | ((uint32_t)o1 << 16);
    packed.y = (uint32_t)o2 | ((uint32_t)o3 << 16);
    ((uint2*)xb)[i] = packed;
  }
}

// ---------------- K2: transpose W [1024][4096] fp32 -> [4096][1024] bf16 ----------------
__global__ void k_transpose_w(const float* __restrict__ w, unsigned short* __restrict__ wt) {
  __shared__ float tile[32][33];
  int n0 = blockIdx.x * 32;
  int k0 = blockIdx.y * 32;
  int c = threadIdx.x & 31, r0 = threadIdx.x >> 5;
  for (int r = r0; r < 32; r += 8)
    tile[r][c] = w[(size_t)(k0 + r) * NG + n0 + c];
  __syncthreads();
  for (int r = r0; r < 32; r += 8)
    wt[(size_t)(n0 + r) * 1024 + k0 + c] = f2bf(tile[c][r]);
}

// ---------------- K3: init (h0->bf16 buf0, bsum, arrival slots) ----------------
__global__ void k_init(const float* __restrict__ h0, const float* __restrict__ b_ih,
                       const float* __restrict__ b_hh, unsigned short* __restrict__ hbuf0,
                       float* __restrict__ bsum, unsigned* __restrict__ arrive) {
  int i = blockIdx.x * 256 + threadIdx.x;
  if (i < NB * DHID) hbuf0[i] = f2bf(h0[i]);
  if (i < NG) bsum[i] = b_ih[i] + b_hh[i];
  if (i < NGRP * WPG) arrive[i] = 0u;
}

// ---------------- K4: pregate GEMM  pg = x_bf16 @ W_ih (permuted layout) ----------------
// Output permuted for k_lstm: idx = (((t*4+gb)*64+w)*1024) + bl*64 + gate*16 + u
//   where rowg = t*64 + b (b = gb*16+bl), colg = gate*1024 + (w*16+u)
template <bool PF32>
__global__ __launch_bounds__(256, 2) void k_gemm_pregates(
    const unsigned short* __restrict__ xb,
    const unsigned short* __restrict__ wt,
    void* __restrict__ pg) {
  __shared__ char lds_raw[32768];
  char* As = lds_raw;
  char* Bs = lds_raw + 16384;

  const int wave = threadIdx.x >> 6;
  const int lane = threadIdx.x & 63;
  const int ln = lane & 15, quad = lane >> 4;
  const int m0 = blockIdx.x * 128;
  const int n0 = blockIdx.y * 128;
  const int mw = (wave >> 1) * 64, nw = (wave & 1) * 64;

  f32x4 acc[4][4] = {};

  for (int kc = 0; kc < 16; ++kc) {
    __syncthreads();
#pragma unroll
    for (int i = 0; i < 4; ++i) {
      int s = wave * 256 + i * 64 + lane;
      int row = s >> 3;
      int kg = (s & 7) ^ (row & 7);
      gll16(xb + (size_t)(m0 + row) * 1024 + kc * 64 + kg * 8, As + s * 16);
      gll16(wt + (size_t)(n0 + row) * 1024 + kc * 64 + kg * 8, Bs + s * 16);
    }
    __syncthreads();

    short8 a[2][4], b[2][4];
#pragma unroll
    for (int kt = 0; kt < 2; ++kt) {
      int kg = kt * 4 + quad;
#pragma unroll
      for (int mt = 0; mt < 4; ++mt) {
        int row = mw + mt * 16 + ln;
        a[kt][mt] = *(const short8*)(As + (row * 8 + (kg ^ (row & 7))) * 16);
      }
#pragma unroll
      for (int nt = 0; nt < 4; ++nt) {
        int row = nw + nt * 16 + ln;
        b[kt][nt] = *(const short8*)(Bs + (row * 8 + (kg ^ (row & 7))) * 16);
      }
    }
#pragma unroll
    for (int kt = 0; kt < 2; ++kt)
#pragma unroll
      for (int mt = 0; mt < 4; ++mt)
#pragma unroll
        for (int nt = 0; nt < 4; ++nt)
          acc[mt][nt] = __builtin_amdgcn_mfma_f32_16x16x32_bf16(a[kt][mt], b[kt][nt], acc[mt][nt], 0, 0, 0);
  }

#pragma unroll
  for (int mt = 0; mt < 4; ++mt)
#pragma unroll
    for (int nt = 0; nt < 4; ++nt)
#pragma unroll
      for (int r = 0; r < 4; ++r) {
        int rowg = m0 + mw + mt * 16 + quad * 4 + r;
        int colg = n0 + nw + nt * 16 + ln;
        int t = rowg >> 6, bglob = rowg & 63;
        int gb = bglob >> 4, bl = bglob & 15;
        int gate = colg >> 10, j = colg & 1023;
        int w = j >> 4, u = j & 15;
        size_t idx = (((size_t)t * NGRP + gb) * WPG + w) * 1024 + (size_t)bl * 64 + gate * 16 + u;
        if (PF32)
          ((float*)pg)[idx] = acc[mt][nt][r];
        else
          ((unsigned short*)pg)[idx] = f2bf(acc[mt][nt][r]);
      }
}

// ---------------- K5: persistent recurrent kernel ----------------
// 256 WGs = 4 independent batch-groups (16 rows) x 64 WGs (16 hidden units).
// wave v computes gate v for the WG's 16 units; W_hh slice register-resident
// (32 short8 = 128 VGPRs/lane). Ballot barrier: per-WG arrival word, release
// store + relaxed 64-lane poll + one acquire fence per step. No atomic RMW.
template <bool PF32>
__global__ __launch_bounds__(256, 1) void k_lstm(
    const unsigned short* __restrict__ whhT,  // [4096][1024] bf16
    const void* __restrict__ pg,
    const float* __restrict__ c0,
    const float* __restrict__ bsum,
    unsigned short* __restrict__ hbuf,  // [2][64][1024] bf16
    float* __restrict__ out,            // [512][64][1024] ++ h_last ++ c_last
    unsigned* __restrict__ arrive) {    // [4][64]
  const int bid = blockIdx.x;
  const int g = bid >> 6;   // batch group
  const int w = bid & 63;   // wg within group
  const int tid = threadIdx.x;
  const int wave = tid >> 6, lane = tid & 63;
  const int ln = lane & 15, quad = lane >> 4;

  __shared__ float gl[4][16][17];  // [gate][batch][unit], padded

  unsigned* arr = arrive + g * WPG;

  // --- W_hh slice -> registers (persistent): wave = gate, ln = unit ---
  short8 wfr[32];
  {
    int col = wave * 1024 + w * 16 + ln;
    const unsigned short* wrow = whhT + (size_t)col * 1024 + quad * 8;
#pragma unroll
    for (int kt = 0; kt < 32; ++kt)
      wfr[kt] = *(const short8*)(wrow + kt * 32);
  }

  // --- per-thread activation state: one (batch,unit) element ---
  const int b = tid >> 4, u = tid & 15;
  const int bg = g * 16 + b;
  const int un = w * 16 + u;
  float cst = c0[(size_t)bg * DHID + un];
  const float bs0 = bsum[un], bs1 = bsum[1024 + un],
              bs2 = bsum[2048 + un], bs3 = bsum[3072 + un];

  const size_t out_hlast = (size_t)TSEQ * NB * DHID;
  const size_t out_clast = out_hlast + (size_t)NB * DHID;

  float p0, p1, p2, p3;
#define LDPG(T)                                                                      \
  {                                                                                  \
    size_t base = (((size_t)(T) * NGRP + g) * WPG + w) * 1024 + (size_t)b * 64 + u;  \
    if (PF32) {                                                                      \
      const float* pp = (const float*)pg;                                            \
      p0 = pp[base]; p1 = pp[base + 16]; p2 = pp[base + 32]; p3 = pp[base + 48];     \
    } else {                                                                         \
      const unsigned short* pp = (const unsigned short*)pg;                          \
      p0 = bf2f(pp[base]); p1 = bf2f(pp[base + 16]);                                 \
      p2 = bf2f(pp[base + 32]); p3 = bf2f(pp[base + 48]);                            \
    }                                                                                \
  }
  LDPG(0);

  for (int t = 0; t < TSEQ; ++t) {
    const unsigned short* hin = hbuf + (size_t)(t & 1) * (NB * DHID);
    unsigned short* hout = hbuf + (size_t)((t + 1) & 1) * (NB * DHID);

    // ---- gates(wave) = h_group[16x1024] @ Whh_slice[1024x16] ----
    f32x4 acc0 = {0,0,0,0}, acc1 = {0,0,0,0}, acc2 = {0,0,0,0}, acc3 = {0,0,0,0};
    const unsigned short* arow = hin + (size_t)(g * 16 + ln) * 1024 + quad * 8;
#pragma unroll
    for (int kt = 0; kt < 32; kt += 4) {
      short8 a0 = *(const short8*)(arow + (kt + 0) * 32);
      short8 a1 = *(const short8*)(arow + (kt + 1) * 32);
      short8 a2 = *(const short8*)(arow + (kt + 2) * 32);
      short8 a3 = *(const short8*)(arow + (kt + 3) * 32);
      acc0 = __builtin_amdgcn_mfma_f32_16x16x32_bf16(a0, wfr[kt + 0], acc0, 0, 0, 0);
      acc1 = __builtin_amdgcn_mfma_f32_16x16x32_bf16(a1, wfr[kt + 1], acc1, 0, 0, 0);
      acc2 = __builtin_amdgcn_mfma_f32_16x16x32_bf16(a2, wfr[kt + 2], acc2, 0, 0, 0);
      acc3 = __builtin_amdgcn_mfma_f32_16x16x32_bf16(a3, wfr[kt + 3], acc3, 0, 0, 0);
    }
    f32x4 asum = (acc0 + acc1) + (acc2 + acc3);
#pragma unroll
    for (int r = 0; r < 4; ++r)
      gl[wave][quad * 4 + r][ln] = asum[r];
    __syncthreads();

    // ---- activation + state update (1 element/thread) ----
    float gi = gl[0][b][u] + p0 + bs0;
    float gf = gl[1][b][u] + p1 + bs1;
    float gg = gl[2][b][u] + p2 + bs2;
    float go = gl[3][b][u] + p3 + bs3;
    float i_ = fsigm(gi), f_ = fsigm(gf), g_ = ftanh(gg), o_ = fsigm(go);
    float cn = f_ * cst + i_ * g_;
    cst = cn;
    float h = o_ * ftanh(cn);
    out[((size_t)t * NB + bg) * DHID + un] = h;
    hout[(size_t)bg * DHID + un] = f2bf(h);
    if (t == TSEQ - 1) {
      out[out_hlast + (size_t)bg * DHID + un] = h;
      out[out_clast + (size_t)bg * DHID + un] = cn;
    }

    // ---- group barrier: ballot-style, no RMW ----
    if (t < TSEQ - 1) {
      __syncthreads();  // all waves' h stores complete + protects gl
      if (tid == 0)
        __hip_atomic_store(&arr[w], (unsigned)(t + 1), __ATOMIC_RELEASE,
                           __HIP_MEMORY_SCOPE_AGENT);
      LDPG(t + 1);  // prefetch next pg; overlaps the spin below
      if (tid < 64) {
        const unsigned tgt = (unsigned)(t + 1);
        while (true) {
          unsigned v = __hip_atomic_load(&arr[tid], __ATOMIC_RELAXED,
                                         __HIP_MEMORY_SCOPE_AGENT);
          if (__all((int)(v >= tgt))) break;
          __builtin_amdgcn_s_sleep(2);
        }
        __builtin_amdgcn_fence(__ATOMIC_ACQUIRE, "agent");
      }
      __syncthreads();
    }
  }
#undef LDPG
}

// ---------------- launcher ----------------
static inline size_t align_up(size_t x, size_t a) { return (x + a - 1) & ~(a - 1); }

extern "C" void kernel_launch(void* const* d_in, const int* in_sizes, int n_in,
                              void* d_out, int out_size, void* d_ws, size_t ws_size,
                              hipStream_t stream) {
  const float* x    = (const float*)d_in[0];
  const float* c0   = (const float*)d_in[1];
  const float* h0   = (const float*)d_in[2];
  const float* W_ih = (const float*)d_in[3];
  const float* W_hh = (const float*)d_in[4];
  const float* b_ih = (const float*)d_in[5];
  const float* b_hh = (const float*)d_in[6];
  float* out = (float*)d_out;

  const size_t pg_elems = (size_t)TSEQ * NB * NG;
  const size_t xb_bytes = (size_t)TSEQ * NB * DI * 2;
  const size_t wt_bytes = (size_t)NG * 1024 * 2;
  const size_t hb_bytes = (size_t)2 * NB * DHID * 2;
  const size_t bsum_bytes = (size_t)NG * 4;
  const size_t arr_bytes = (size_t)NGRP * WPG * 4;

  auto layout = [&](size_t pg_bytes, size_t* offs) {
    size_t o = 0;
    offs[0] = o; o = align_up(o + pg_bytes, 256);
    offs[1] = o; o = align_up(o + xb_bytes, 256);
    offs[2] = o; o = align_up(o + wt_bytes, 256);
    offs[3] = o; o = align_up(o + wt_bytes, 256);
    offs[4] = o; o = align_up(o + hb_bytes, 256);
    offs[5] = o; o = align_up(o + bsum_bytes, 256);
    offs[6] = o; o = align_up(o + arr_bytes, 256);
    return o;
  };
  size_t offs[7];
  size_t need_f32 = layout(pg_elems * 4, offs);
  bool pf32 = ws_size >= need_f32;
  if (!pf32) layout(pg_elems * 2, offs);

  char* ws = (char*)d_ws;
  void* pg = ws + offs[0];
  unsigned short* xb   = (unsigned short*)(ws + offs[1]);
  unsigned short* wihT = (unsigned short*)(ws + offs[2]);
  unsigned short* whhT = (unsigned short*)(ws + offs[3]);
  unsigned short* hbuf = (unsigned short*)(ws + offs[4]);
  float* bsum = (float*)(ws + offs[5]);
  unsigned* arrive = (unsigned*)(ws + offs[6]);

  k_convert_x<<<2048, 256, 0, stream>>>(x, xb, (int)((size_t)TSEQ * NB * DI / 4));
  k_transpose_w<<<dim3(NG / 32, 1024 / 32), 256, 0, stream>>>(W_ih, wihT);
  k_transpose_w<<<dim3(NG / 32, 1024 / 32), 256, 0, stream>>>(W_hh, whhT);
  k_init<<<(NB * DHID + 255) / 256, 256, 0, stream>>>(h0, b_ih, b_hh, hbuf, bsum, arrive);

  dim3 ggrid(TSEQ * NB / 128, NG / 128);
  if (pf32)
    k_gemm_pregates<true><<<ggrid, 256, 0, stream>>>(xb, wihT, pg);
  else
    k_gemm_pregates<false><<<ggrid, 256, 0, stream>>>(xb, wihT, pg);

  if (pf32)
    k_lstm<true><<<NWGS, 256, 0, stream>>>(whhT, pg, c0, bsum, hbuf, out, arrive);
  else
    k_lstm<false><<<NWGS, 256, 0, stream>>>(whhT, pg, c0, bsum, hbuf, out, arrive);
}

// Round 4
// 7207.157 us; speedup vs baseline: 1.9058x; 1.0208x over previous
//
#include <hip/hip_runtime.h>
#include <stdint.h>
#include <stddef.h>

#define TSEQ 512
#define NB   64
#define DI   1024
#define DHID 1024
#define NG   4096
#define NGRP 4     // independent batch groups (16 batch rows each)
#define WPG  64    // workgroups per group (16 hidden units each)
#define NWGS 256   // total persistent workgroups (1 per CU)

typedef __attribute__((ext_vector_type(8))) short short8;
typedef __attribute__((ext_vector_type(4))) float f32x4;

__device__ __forceinline__ unsigned short f2bf(float f) {
  union { float f; uint32_t u; } v; v.f = f;
  uint32_t u = v.u;
  uint32_t r = u + 0x7fffu + ((u >> 16) & 1u);
  return (unsigned short)(r >> 16);
}
__device__ __forceinline__ float bf2f(unsigned short b) {
  union { uint32_t u; float f; } v; v.u = ((uint32_t)b) << 16;
  return v.f;
}
__device__ __forceinline__ float fsigm(float x) { return 1.0f / (1.0f + __expf(-x)); }
__device__ __forceinline__ float ftanh(float x) { return 1.0f - 2.0f / (__expf(2.0f * x) + 1.0f); }

__device__ __forceinline__ void gll16(const void* g, void* l) {
  __builtin_amdgcn_global_load_lds(
      (const __attribute__((address_space(1))) void*)g,
      (__attribute__((address_space(3))) void*)l, 16, 0, 0);
}

// ---------------- K1: x fp32 -> bf16 ----------------
__global__ void k_convert_x(const float* __restrict__ x, unsigned short* __restrict__ xb, int n4) {
  int idx = blockIdx.x * blockDim.x + threadIdx.x;
  int stride = gridDim.x * blockDim.x;
  const float4* xf = (const float4*)x;
  for (int i = idx; i < n4; i += stride) {
    float4 v = xf[i];
    unsigned short o0 = f2bf(v.x), o1 = f2bf(v.y), o2 = f2bf(v.z), o3 = f2bf(v.w);
    uint2 packed;
    packed.x = (uint32_t)o0 | ((uint32_t)o1 << 16);
    packed.y = (uint32_t)o2 | ((uint32_t)o3 << 16);
    ((uint2*)xb)[i] = packed;
  }
}

// ---------------- K2: transpose W [1024][4096] fp32 -> [4096][1024] bf16 ----------------
__global__ void k_transpose_w(const float* __restrict__ w, unsigned short* __restrict__ wt) {
  __shared__ float tile[32][33];
  int n0 = blockIdx.x * 32;
  int k0 = blockIdx.y * 32;
  int c = threadIdx.x & 31, r0 = threadIdx.x >> 5;
  for (int r = r0; r < 32; r += 8)
    tile[r][c] = w[(size_t)(k0 + r) * NG + n0 + c];
  __syncthreads();
  for (int r = r0; r < 32; r += 8)
    wt[(size_t)(n0 + r) * 1024 + k0 + c] = f2bf(tile[c][r]);
}

// ---------------- K3: init (h0->bf16 buf0, bsum, arrival slots) ----------------
__global__ void k_init(const float* __restrict__ h0, const float* __restrict__ b_ih,
                       const float* __restrict__ b_hh, unsigned short* __restrict__ hbuf0,
                       float* __restrict__ bsum, unsigned* __restrict__ arrive) {
  int i = blockIdx.x * 256 + threadIdx.x;
  if (i < NB * DHID) hbuf0[i] = f2bf(h0[i]);
  if (i < NG) bsum[i] = b_ih[i] + b_hh[i];
  if (i < NGRP * WPG) arrive[i] = 0u;
}

// ---------------- K4: pregate GEMM  pg = x_bf16 @ W_ih (permuted layout) ----------------
// Output permuted for k_lstm: idx = (((t*4+gb)*64+w)*1024) + bl*64 + gate*16 + u
template <bool PF32>
__global__ __launch_bounds__(256, 2) void k_gemm_pregates(
    const unsigned short* __restrict__ xb,
    const unsigned short* __restrict__ wt,
    void* __restrict__ pg) {
  __shared__ char lds_raw[32768];
  char* As = lds_raw;
  char* Bs = lds_raw + 16384;

  const int wave = threadIdx.x >> 6;
  const int lane = threadIdx.x & 63;
  const int ln = lane & 15, quad = lane >> 4;
  const int m0 = blockIdx.x * 128;
  const int n0 = blockIdx.y * 128;
  const int mw = (wave >> 1) * 64, nw = (wave & 1) * 64;

  f32x4 acc[4][4] = {};

  for (int kc = 0; kc < 16; ++kc) {
    __syncthreads();
#pragma unroll
    for (int i = 0; i < 4; ++i) {
      int s = wave * 256 + i * 64 + lane;
      int row = s >> 3;
      int kg = (s & 7) ^ (row & 7);
      gll16(xb + (size_t)(m0 + row) * 1024 + kc * 64 + kg * 8, As + s * 16);
      gll16(wt + (size_t)(n0 + row) * 1024 + kc * 64 + kg * 8, Bs + s * 16);
    }
    __syncthreads();

    short8 a[2][4], b[2][4];
#pragma unroll
    for (int kt = 0; kt < 2; ++kt) {
      int kg = kt * 4 + quad;
#pragma unroll
      for (int mt = 0; mt < 4; ++mt) {
        int row = mw + mt * 16 + ln;
        a[kt][mt] = *(const short8*)(As + (row * 8 + (kg ^ (row & 7))) * 16);
      }
#pragma unroll
      for (int nt = 0; nt < 4; ++nt) {
        int row = nw + nt * 16 + ln;
        b[kt][nt] = *(const short8*)(Bs + (row * 8 + (kg ^ (row & 7))) * 16);
      }
    }
#pragma unroll
    for (int kt = 0; kt < 2; ++kt)
#pragma unroll
      for (int mt = 0; mt < 4; ++mt)
#pragma unroll
        for (int nt = 0; nt < 4; ++nt)
          acc[mt][nt] = __builtin_amdgcn_mfma_f32_16x16x32_bf16(a[kt][mt], b[kt][nt], acc[mt][nt], 0, 0, 0);
  }

#pragma unroll
  for (int mt = 0; mt < 4; ++mt)
#pragma unroll
    for (int nt = 0; nt < 4; ++nt)
#pragma unroll
      for (int r = 0; r < 4; ++r) {
        int rowg = m0 + mw + mt * 16 + quad * 4 + r;
        int colg = n0 + nw + nt * 16 + ln;
        int t = rowg >> 6, bglob = rowg & 63;
        int gb = bglob >> 4, bl = bglob & 15;
        int gate = colg >> 10, j = colg & 1023;
        int w = j >> 4, u = j & 15;
        size_t idx = (((size_t)t * NGRP + gb) * WPG + w) * 1024 + (size_t)bl * 64 + gate * 16 + u;
        if (PF32)
          ((float*)pg)[idx] = acc[mt][nt][r];
        else
          ((unsigned short*)pg)[idx] = f2bf(acc[mt][nt][r]);
      }
}

// ---------------- K5: persistent recurrent kernel ----------------
// 256 WGs = 4 batch-groups (16 rows) x 64 WGs (16 hidden units).
// W_hh slice (128 KB) staged ONCE into LDS in identity fragment layout
// [gate][kt][lane]*16B -> per-step reads are ds_read_b128 at base+lane*16
// (m134-optimal, immune to coherence fences and register rematerialization).
// A-frags (h) = 32 outstanding global loads/lane. Ballot barrier, no RMW.
template <bool PF32>
__global__ __launch_bounds__(256, 1) void k_lstm(
    const unsigned short* __restrict__ whhT,  // [4096][1024] bf16
    const void* __restrict__ pg,
    const float* __restrict__ c0,
    const float* __restrict__ bsum,
    unsigned short* __restrict__ hbuf,  // [2][64][1024] bf16
    float* __restrict__ out,            // [512][64][1024] ++ h_last ++ c_last
    unsigned* __restrict__ arrive) {    // [4][64]
  const int bid = blockIdx.x;
  const int g = bid >> 6;   // batch group
  const int w = bid & 63;   // wg within group
  const int tid = threadIdx.x;
  const int wave = tid >> 6, lane = tid & 63;
  const int ln = lane & 15, quad = lane >> 4;

  __shared__ char wlds[4 * 32 * 1024];   // 128 KB: [gate][kt][lane]*16B
  __shared__ float gl[4][16][17];        // [gate][batch][unit], padded

  unsigned* arr = arrive + g * WPG;

  // --- stage W_hh slice -> LDS (once). gll16: dst = wave-uniform + lane*16. ---
  {
    const unsigned short* src = whhT + (size_t)(wave * 1024 + w * 16 + ln) * 1024 + quad * 8;
    char* dst = wlds + wave * 32768;
#pragma unroll
    for (int kt = 0; kt < 32; ++kt)
      gll16(src + kt * 32, dst + kt * 1024);
  }
  __syncthreads();

  // --- per-thread activation state: one (batch,unit) element ---
  const int b = tid >> 4, u = tid & 15;
  const int bg = g * 16 + b;
  const int un = w * 16 + u;
  float cst = c0[(size_t)bg * DHID + un];
  const float bs0 = bsum[un], bs1 = bsum[1024 + un],
              bs2 = bsum[2048 + un], bs3 = bsum[3072 + un];

  const size_t out_hlast = (size_t)TSEQ * NB * DHID;
  const size_t out_clast = out_hlast + (size_t)NB * DHID;

  float p0, p1, p2, p3;
#define LDPG(T)                                                                      \
  {                                                                                  \
    size_t base = (((size_t)(T) * NGRP + g) * WPG + w) * 1024 + (size_t)b * 64 + u;  \
    if (PF32) {                                                                      \
      const float* pp = (const float*)pg;                                            \
      p0 = pp[base]; p1 = pp[base + 16]; p2 = pp[base + 32]; p3 = pp[base + 48];     \
    } else {                                                                         \
      const unsigned short* pp = (const unsigned short*)pg;                          \
      p0 = bf2f(pp[base]); p1 = bf2f(pp[base + 16]);                                 \
      p2 = bf2f(pp[base + 32]); p3 = bf2f(pp[base + 48]);                            \
    }                                                                                \
  }
  LDPG(0);

  const char* wb = wlds + wave * 32768 + lane * 16;

  for (int t = 0; t < TSEQ; ++t) {
    const unsigned short* hin = hbuf + (size_t)(t & 1) * (NB * DHID);
    unsigned short* hout = hbuf + (size_t)((t + 1) & 1) * (NB * DHID);

    // ---- A-frags: issue all 32 h loads up front (outstanding in vmcnt) ----
    short8 afr[32];
    const unsigned short* arow = hin + (size_t)(g * 16 + ln) * 1024 + quad * 8;
#pragma unroll
    for (int kt = 0; kt < 32; ++kt)
      afr[kt] = *(const short8*)(arow + kt * 32);

    // ---- gates(wave) = h_group @ Whh_slice; B from LDS identity layout ----
    f32x4 acc0 = {0,0,0,0}, acc1 = {0,0,0,0}, acc2 = {0,0,0,0}, acc3 = {0,0,0,0};
#pragma unroll
    for (int kt = 0; kt < 32; kt += 4) {
      short8 b0 = *(const short8*)(wb + (kt + 0) * 1024);
      short8 b1 = *(const short8*)(wb + (kt + 1) * 1024);
      short8 b2 = *(const short8*)(wb + (kt + 2) * 1024);
      short8 b3 = *(const short8*)(wb + (kt + 3) * 1024);
      acc0 = __builtin_amdgcn_mfma_f32_16x16x32_bf16(afr[kt + 0], b0, acc0, 0, 0, 0);
      acc1 = __builtin_amdgcn_mfma_f32_16x16x32_bf16(afr[kt + 1], b1, acc1, 0, 0, 0);
      acc2 = __builtin_amdgcn_mfma_f32_16x16x32_bf16(afr[kt + 2], b2, acc2, 0, 0, 0);
      acc3 = __builtin_amdgcn_mfma_f32_16x16x32_bf16(afr[kt + 3], b3, acc3, 0, 0, 0);
    }
    f32x4 asum = (acc0 + acc1) + (acc2 + acc3);
#pragma unroll
    for (int r = 0; r < 4; ++r)
      gl[wave][quad * 4 + r][ln] = asum[r];
    __syncthreads();

    // ---- activation + state update (1 element/thread) ----
    float gi = gl[0][b][u] + p0 + bs0;
    float gf = gl[1][b][u] + p1 + bs1;
    float gg = gl[2][b][u] + p2 + bs2;
    float go = gl[3][b][u] + p3 + bs3;
    float i_ = fsigm(gi), f_ = fsigm(gf), g_ = ftanh(gg), o_ = fsigm(go);
    float cn = f_ * cst + i_ * g_;
    cst = cn;
    float h = o_ * ftanh(cn);
    out[((size_t)t * NB + bg) * DHID + un] = h;
    hout[(size_t)bg * DHID + un] = f2bf(h);
    if (t == TSEQ - 1) {
      out[out_hlast + (size_t)bg * DHID + un] = h;
      out[out_clast + (size_t)bg * DHID + un] = cn;
    }

    // ---- group barrier: ballot-style, no RMW ----
    if (t < TSEQ - 1) {
      __syncthreads();  // drains hout stores (vmcnt 0) + protects gl
      if (tid == 0)
        __hip_atomic_store(&arr[w], (unsigned)(t + 1), __ATOMIC_RELEASE,
                           __HIP_MEMORY_SCOPE_AGENT);
      LDPG(t + 1);  // prefetch next pg; overlaps the spin below
      if (tid < 64) {
        const unsigned tgt = (unsigned)(t + 1);
        while (true) {
          unsigned v = __hip_atomic_load(&arr[tid], __ATOMIC_RELAXED,
                                         __HIP_MEMORY_SCOPE_AGENT);
          if (__all((int)(v >= tgt))) break;
          __builtin_amdgcn_s_sleep(2);
        }
        __builtin_amdgcn_fence(__ATOMIC_ACQUIRE, "agent");
      }
      __syncthreads();
    }
  }
#undef LDPG
}

// ---------------- launcher ----------------
static inline size_t align_up(size_t x, size_t a) { return (x + a - 1) & ~(a - 1); }

extern "C" void kernel_launch(void* const* d_in, const int* in_sizes, int n_in,
                              void* d_out, int out_size, void* d_ws, size_t ws_size,
                              hipStream_t stream) {
  const float* x    = (const float*)d_in[0];
  const float* c0   = (const float*)d_in[1];
  const float* h0   = (const float*)d_in[2];
  const float* W_ih = (const float*)d_in[3];
  const float* W_hh = (const float*)d_in[4];
  const float* b_ih = (const float*)d_in[5];
  const float* b_hh = (const float*)d_in[6];
  float* out = (float*)d_out;

  const size_t pg_elems = (size_t)TSEQ * NB * NG;
  const size_t xb_bytes = (size_t)TSEQ * NB * DI * 2;
  const size_t wt_bytes = (size_t)NG * 1024 * 2;
  const size_t hb_bytes = (size_t)2 * NB * DHID * 2;
  const size_t bsum_bytes = (size_t)NG * 4;
  const size_t arr_bytes = (size_t)NGRP * WPG * 4;

  auto layout = [&](size_t pg_bytes, size_t* offs) {
    size_t o = 0;
    offs[0] = o; o = align_up(o + pg_bytes, 256);
    offs[1] = o; o = align_up(o + xb_bytes, 256);
    offs[2] = o; o = align_up(o + wt_bytes, 256);
    offs[3] = o; o = align_up(o + wt_bytes, 256);
    offs[4] = o; o = align_up(o + hb_bytes, 256);
    offs[5] = o; o = align_up(o + bsum_bytes, 256);
    offs[6] = o; o = align_up(o + arr_bytes, 256);
    return o;
  };
  size_t offs[7];
  size_t need_f32 = layout(pg_elems * 4, offs);
  bool pf32 = ws_size >= need_f32;
  if (!pf32) layout(pg_elems * 2, offs);

  char* ws = (char*)d_ws;
  void* pg = ws + offs[0];
  unsigned short* xb   = (unsigned short*)(ws + offs[1]);
  unsigned short* wihT = (unsigned short*)(ws + offs[2]);
  unsigned short* whhT = (unsigned short*)(ws + offs[3]);
  unsigned short* hbuf = (unsigned short*)(ws + offs[4]);
  float* bsum = (float*)(ws + offs[5]);
  unsigned* arrive = (unsigned*)(ws + offs[6]);

  k_convert_x<<<2048, 256, 0, stream>>>(x, xb, (int)((size_t)TSEQ * NB * DI / 4));
  k_transpose_w<<<dim3(NG / 32, 1024 / 32), 256, 0, stream>>>(W_ih, wihT);
  k_transpose_w<<<dim3(NG / 32, 1024 / 32), 256, 0, stream>>>(W_hh, whhT);
  k_init<<<(NB * DHID + 255) / 256, 256, 0, stream>>>(h0, b_ih, b_hh, hbuf, bsum, arrive);

  dim3 ggrid(TSEQ * NB / 128, NG / 128);
  if (pf32)
    k_gemm_pregates<true><<<ggrid, 256, 0, stream>>>(xb, wihT, pg);
  else
    k_gemm_pregates<false><<<ggrid, 256, 0, stream>>>(xb, wihT, pg);

  if (pf32)
    k_lstm<true><<<NWGS, 256, 0, stream>>>(whhT, pg, c0, bsum, hbuf, out, arrive);
  else
    k_lstm<false><<<NWGS, 256, 0, stream>>>(whhT, pg, c0, bsum, hbuf, out, arrive);
}